// Round 11
// baseline (305.962 us; speedup 1.0000x reference)
//
#include <hip/hip_runtime.h>
#include <hip/hip_fp16.h>
#include <math.h>

// Problem constants
#define BB 256
#define LL 256
#define CC 128
#define HIDD 128
#define HH 4
#define DD 32
#define EE 4096
#define NN (BB*CC)          // 32768 nodes
#define LN_EPS 1e-5f

typedef short bf16x8 __attribute__((ext_vector_type(8)));
typedef _Float16 f16x8 __attribute__((ext_vector_type(8)));
typedef float f32x4 __attribute__((ext_vector_type(4)));

// ---------------------------------------------------------------------------
// helpers
// ---------------------------------------------------------------------------
__device__ __forceinline__ unsigned bfr(float f) {        // fp32 -> bf16 bits, RNE
    unsigned x = __float_as_uint(f);
    return (x + 0x7FFFu + ((x >> 16) & 1u)) >> 16;
}
__device__ __forceinline__ unsigned pack2(float a, float b) { return bfr(a) | (bfr(b) << 16); }
__device__ __forceinline__ float b2f(unsigned u) { return __uint_as_float(u << 16); }

// ---------------------------------------------------------------------------
// MFMA GEMM building blocks. Tiles are M x 128 with 16B chunks, physical
// chunk = c ^ (row&7). GRID of 2 blocks per CU (M split in half) gives two
// INDEPENDENT barrier domains per CU — R10 showed 8 waves in ONE block
// (shared barriers) is a null: the whole CU drains at every __syncthreads.
// ---------------------------------------------------------------------------
__device__ __forceinline__ void stage_a64(ushort* lds, const ushort* src, int ldm, int t) {
    #pragma unroll
    for (int i = 0; i < 4; ++i) {
        int flat = i*256 + t;                   // 64 rows x 16 chunks
        int r = flat >> 4, c = flat & 15;
        uint4 pk = *(const uint4*)(src + (size_t)r*ldm + c*8);
        *(uint4*)&lds[((r*16) + (c ^ (r & 7)))*8] = pk;
    }
}
__device__ __forceinline__ void stage_b128(ushort* lds, const ushort* src, int ldm, int t) {
    #pragma unroll
    for (int i = 0; i < 8; ++i) {
        int flat = i*256 + t;                   // 128 rows x 16 chunks
        int r = flat >> 4, c = flat & 15;
        uint4 pk = *(const uint4*)(src + (size_t)r*ldm + c*8);
        *(uint4*)&lds[((r*16) + (c ^ (r & 7)))*8] = pk;
    }
}
// 64x128 tile: 4 waves, wave w owns rows w*16..+15 (1 m-frag x 8 n-frags)
__device__ __forceinline__ void mfma_64x128(const ushort* Als, const ushort* Bls,
                                            f32x4 acc[8], int w, int lane) {
    int mr = lane & 15, quad = lane >> 4;
    int m = w*16 + mr;
    #pragma unroll
    for (int ks = 0; ks < 4; ++ks) {
        int ca = ks*4 + quad;
        bf16x8 a = *(const bf16x8*)&Als[((m*16) + (ca ^ (m & 7)))*8];
        bf16x8 b[8];
        #pragma unroll
        for (int nf = 0; nf < 8; ++nf) {
            int n = nf*16 + mr;
            b[nf] = *(const bf16x8*)&Bls[((n*16) + (ca ^ (n & 7)))*8];
        }
        #pragma unroll
        for (int nf = 0; nf < 8; ++nf)
            acc[nf] = __builtin_amdgcn_mfma_f32_16x16x32_bf16(a, b[nf], acc[nf], 0, 0, 0);
    }
}
// 128x128 tile: 4 waves, wave w owns rows w*32..+31 (2 m-frags x 8 n-frags)
__device__ __forceinline__ void mfma_tile_128(const ushort* Als, const ushort* Bls,
                                              f32x4 acc[2][8], int w, int lane) {
    int mr = lane & 15, quad = lane >> 4;
    #pragma unroll
    for (int ks = 0; ks < 4; ++ks) {
        int ca = ks*4 + quad;
        bf16x8 a[2], b[8];
        #pragma unroll
        for (int mf = 0; mf < 2; ++mf) {
            int m = w*32 + mf*16 + mr;
            a[mf] = *(const bf16x8*)&Als[((m*16) + (ca ^ (m & 7)))*8];
        }
        #pragma unroll
        for (int nf = 0; nf < 8; ++nf) {
            int n = nf*16 + mr;
            b[nf] = *(const bf16x8*)&Bls[((n*16) + (ca ^ (n & 7)))*8];
        }
        #pragma unroll
        for (int mf = 0; mf < 2; ++mf)
            #pragma unroll
            for (int nf = 0; nf < 8; ++nf)
                acc[mf][nf] = __builtin_amdgcn_mfma_f32_16x16x32_bf16(a[mf], b[nf], acc[mf][nf], 0, 0, 0);
    }
}
#define ZERO_ACC8(acc) { _Pragma("unroll") for (int j_=0;j_<8;++j_) acc[j_] = (f32x4){0.f,0.f,0.f,0.f}; }
#define ZERO_ACC28(acc) { _Pragma("unroll") for (int i_=0;i_<2;++i_) { _Pragma("unroll") for (int j_=0;j_<8;++j_) acc[i_][j_] = (f32x4){0.f,0.f,0.f,0.f}; } }

// ---------------------------------------------------------------------------
// Fused epilogue, 64-node variant: 4 threads/node (nl = t>>2 in 0..63,
// fq = t&3 = head). Normalize xagg by Sg, bias -> ELU -> residual -> LN
// (4-lane shfl reduce), stage bf16 rows into a 64-row LDS tile, opt. write h.
// ---------------------------------------------------------------------------
__device__ __forceinline__ void epilogue64(const __half* __restrict__ xagg,
                                           const float* __restrict__ gbias,
                                           const float* __restrict__ ln_g,
                                           const float* __restrict__ ln_b,
                                           const float* __restrict__ Sg_b,
                                           ushort* __restrict__ hmat,
                                           ushort* __restrict__ tile,
                                           int b, int n0, int t, bool write_h) {
    int nl = t >> 2, fq = t & 3;
    int node = b*CC + n0 + nl;
    const __half* xa = xagg + (size_t)node*HIDD + fq*32;
    ushort* hp = hmat + (size_t)node*HIDD + fq*32;
    const float* gb = gbias + fq*32;
    float isv = Sg_b[fq*CC + n0 + nl];

    __half2 hv[16];
    float sum = 0.f;
    #pragma unroll
    for (int c = 0; c < 4; ++c) {
        uint4 xu = *(const uint4*)&xa[c*8];
        uint4 hu = *(const uint4*)&hp[c*8];
        const __half2* xp2 = (const __half2*)&xu;
        const ushort* hs = (const ushort*)&hu;
        float gv[8];
        *(float4*)&gv[0] = *(const float4*)&gb[c*8];
        *(float4*)&gv[4] = *(const float4*)&gb[c*8 + 4];
        #pragma unroll
        for (int i = 0; i < 4; ++i) {
            float o0 = __low2float(xp2[i]) * isv + gv[2*i];
            float o1 = __high2float(xp2[i]) * isv + gv[2*i+1];
            o0 = o0 > 0.f ? o0 : (__expf(o0) - 1.f);
            o1 = o1 > 0.f ? o1 : (__expf(o1) - 1.f);
            float v0 = b2f((unsigned)hs[2*i]) + o0;
            float v1 = b2f((unsigned)hs[2*i+1]) + o1;
            sum += v0 + v1;
            hv[c*4 + i] = __floats2half2_rn(v0, v1);
        }
    }
    sum += __shfl_xor(sum, 1);
    sum += __shfl_xor(sum, 2);
    float mean = sum * 0.0078125f;
    float q = 0.f;
    #pragma unroll
    for (int i = 0; i < 16; ++i) {
        float d0 = __low2float(hv[i]) - mean;
        float d1 = __high2float(hv[i]) - mean;
        q += d0*d0 + d1*d1;
    }
    q += __shfl_xor(q, 1);
    q += __shfl_xor(q, 2);
    float var = q * 0.0078125f;
    float rs = rsqrtf(var + LN_EPS);
    const float* lg = ln_g + fq*32;
    const float* lb = ln_b + fq*32;
    #pragma unroll
    for (int c = 0; c < 4; ++c) {
        float gv[8], bv[8];
        *(float4*)&gv[0] = *(const float4*)&lg[c*8];
        *(float4*)&gv[4] = *(const float4*)&lg[c*8 + 4];
        *(float4*)&bv[0] = *(const float4*)&lb[c*8];
        *(float4*)&bv[4] = *(const float4*)&lb[c*8 + 4];
        __align__(16) ushort ov[8];
        #pragma unroll
        for (int i = 0; i < 4; ++i) {
            float d0 = __low2float(hv[c*4 + i]) - mean;
            float d1 = __high2float(hv[c*4 + i]) - mean;
            ov[2*i]   = (ushort)bfr(d0*rs*gv[2*i]   + bv[2*i]);
            ov[2*i+1] = (ushort)bfr(d1*rs*gv[2*i+1] + bv[2*i+1]);
        }
        int cg = fq*4 + c;
        *(uint4*)&tile[((nl*16) + (cg ^ (nl & 7)))*8] = *(uint4*)ov;
        if (write_h) *(uint4*)&hp[c*8] = *(uint4*)ov;
    }
}

// ---------------------------------------------------------------------------
// Fused epilogue, 128-node variant: 2 threads/node (nl = t>>1, fh = t&1),
// each owns 64 features. Same math; stages a 128-row tile. No h write.
// ---------------------------------------------------------------------------
__device__ __forceinline__ void epilogue128(const __half* __restrict__ xagg,
                                            const float* __restrict__ gbias,
                                            const float* __restrict__ ln_g,
                                            const float* __restrict__ ln_b,
                                            const float* __restrict__ Sg_b,
                                            const ushort* __restrict__ hmat,
                                            ushort* __restrict__ tile,
                                            int b, int t) {
    int nl = t >> 1, fh = t & 1;
    int node = b*CC + nl;
    const __half* xa = xagg + (size_t)node*HIDD + fh*64;
    const ushort* hp = hmat + (size_t)node*HIDD + fh*64;
    const float* gb = gbias + fh*64;
    float is0 = Sg_b[(fh*2 + 0)*CC + nl];
    float is1 = Sg_b[(fh*2 + 1)*CC + nl];

    __half2 hv[32];
    float sum = 0.f;
    #pragma unroll
    for (int c = 0; c < 8; ++c) {
        float isv = (c < 4) ? is0 : is1;
        uint4 xu = *(const uint4*)&xa[c*8];
        uint4 hu = *(const uint4*)&hp[c*8];
        const __half2* xp2 = (const __half2*)&xu;
        const ushort* hs = (const ushort*)&hu;
        float gv[8];
        *(float4*)&gv[0] = *(const float4*)&gb[c*8];
        *(float4*)&gv[4] = *(const float4*)&gb[c*8 + 4];
        #pragma unroll
        for (int i = 0; i < 4; ++i) {
            float o0 = __low2float(xp2[i]) * isv + gv[2*i];
            float o1 = __high2float(xp2[i]) * isv + gv[2*i+1];
            o0 = o0 > 0.f ? o0 : (__expf(o0) - 1.f);
            o1 = o1 > 0.f ? o1 : (__expf(o1) - 1.f);
            float v0 = b2f((unsigned)hs[2*i]) + o0;
            float v1 = b2f((unsigned)hs[2*i+1]) + o1;
            sum += v0 + v1;
            hv[c*4 + i] = __floats2half2_rn(v0, v1);
        }
    }
    float mean = (sum + __shfl_xor(sum, 1)) * 0.0078125f;
    float q = 0.f;
    #pragma unroll
    for (int i = 0; i < 32; ++i) {
        float d0 = __low2float(hv[i]) - mean;
        float d1 = __high2float(hv[i]) - mean;
        q += d0*d0 + d1*d1;
    }
    float var = (q + __shfl_xor(q, 1)) * 0.0078125f;
    float rs = rsqrtf(var + LN_EPS);
    const float* lg = ln_g + fh*64;
    const float* lb = ln_b + fh*64;
    #pragma unroll
    for (int c = 0; c < 8; ++c) {
        float gv[8], bv[8];
        *(float4*)&gv[0] = *(const float4*)&lg[c*8];
        *(float4*)&gv[4] = *(const float4*)&lg[c*8 + 4];
        *(float4*)&bv[0] = *(const float4*)&lb[c*8];
        *(float4*)&bv[4] = *(const float4*)&lb[c*8 + 4];
        __align__(16) ushort ov[8];
        #pragma unroll
        for (int i = 0; i < 4; ++i) {
            float d0 = __low2float(hv[c*4 + i]) - mean;
            float d1 = __high2float(hv[c*4 + i]) - mean;
            ov[2*i]   = (ushort)bfr(d0*rs*gv[2*i]   + bv[2*i]);
            ov[2*i+1] = (ushort)bfr(d1*rs*gv[2*i+1] + bv[2*i+1]);
        }
        int cg = fh*8 + c;
        *(uint4*)&tile[((nl*16) + (cg ^ (nl & 7)))*8] = *(uint4*)ov;
    }
}

// ---------------------------------------------------------------------------
// K0: weight prep (blocks 0..63) + dense multiplicity table (block 64).
// ---------------------------------------------------------------------------
__global__ __launch_bounds__(256) void prep_weights(const float* __restrict__ emb_W,
                                                    const float* __restrict__ lWl,
                                                    const float* __restrict__ lWr,
                                                    const float* __restrict__ pW,
                                                    const int* __restrict__ edge,
                                                    ushort* __restrict__ WembT,
                                                    ushort* __restrict__ WlrT,
                                                    ushort* __restrict__ WpT,
                                                    __half* __restrict__ mult_ds) {
    __shared__ int cnt[CC*CC];              // 64KB (used by block 64 only)
    int t = threadIdx.x;
    if (blockIdx.x == 64) {
        for (int i = t; i < CC*CC; i += 256) cnt[i] = 0;
        __syncthreads();
        for (int j = t; j < EE; j += 256) {
            int s = edge[j], d = edge[EE + j];
            atomicAdd(&cnt[s*CC + d], 1);
        }
        __syncthreads();
        for (int o = t; o < CC*CC; o += 256) {
            int dstc = o >> 7, srcc = o & 127;
            int c = cnt[srcc*CC + dstc] + ((srcc == dstc) ? 1 : 0);
            mult_ds[o] = __float2half((float)c);
        }
        return;
    }
    int gid = blockIdx.x * 256 + t;
    float v[8];
    if (gid < 4096) {                       // emb: 128 f x 32 l-chunks
        int f = gid >> 5, ch = gid & 31;
        #pragma unroll
        for (int j = 0; j < 8; ++j) v[j] = emb_W[(size_t)(ch*8 + j)*HIDD + f];
        uint4 pk; pk.x = pack2(v[0],v[1]); pk.y = pack2(v[2],v[3]);
        pk.z = pack2(v[4],v[5]); pk.w = pack2(v[6],v[7]);
        *(uint4*)&WembT[(size_t)f*LL + ch*8] = pk;
    } else if (gid < 12288) {               // lin: 4 mats x 128 f x 16 k-chunks
        int g = gid - 4096;
        int mat = g >> 11, f = (g >> 4) & 127, ch = g & 15;
        const float* src = ((mat & 1) ? lWr : lWl) + (size_t)(mat >> 1)*HIDD*HIDD;
        #pragma unroll
        for (int j = 0; j < 8; ++j) v[j] = src[(size_t)(ch*8 + j)*HIDD + f];
        uint4 pk; pk.x = pack2(v[0],v[1]); pk.y = pack2(v[2],v[3]);
        pk.z = pack2(v[4],v[5]); pk.w = pack2(v[6],v[7]);
        *(uint4*)&WlrT[(size_t)mat*HIDD*HIDD + (size_t)f*HIDD + ch*8] = pk;
    } else {                                // proj: 256 l x 16 k-chunks
        int g = gid - 12288;
        int l = g >> 4, ch = g & 15;
        #pragma unroll
        for (int j = 0; j < 8; ++j) v[j] = pW[(size_t)(ch*8 + j)*LL + l];
        uint4 pk; pk.x = pack2(v[0],v[1]); pk.y = pack2(v[2],v[3]);
        pk.z = pack2(v[4],v[5]); pk.w = pack2(v[6],v[7]);
        *(uint4*)&WpT[(size_t)l*HIDD + ch*8] = pk;
    }
}

// ---------------------------------------------------------------------------
// K2: embedding GEMM, M-split: block (chalf, b) computes 64 channels x 128
// features. Grid 512 = 2 blocks/CU (independent barriers). LDS 48KB.
// ---------------------------------------------------------------------------
__global__ __launch_bounds__(256) void embed_mfma(const float* __restrict__ x,
                                                  const ushort* __restrict__ WembT,
                                                  const float* __restrict__ bias,
                                                  ushort* __restrict__ hout) {
    __shared__ __align__(16) ushort Als[64*16*8];     // 16KB
    __shared__ __align__(16) ushort Bls[128*16*8];    // 32KB
    int chalf = blockIdx.x, b = blockIdx.y;
    int t = threadIdx.x, lane = t & 63, w = t >> 6;
    f32x4 acc[8];
    ZERO_ACC8(acc)
    #pragma unroll
    for (int kh = 0; kh < 2; ++kh) {
        if (kh) __syncthreads();
        const float4* x4 = (const float4*)(x + (size_t)b*LL*CC + (size_t)kh*128*CC);
        int rot = (t >> 3) & 3;
        #pragma unroll
        for (int i = 0; i < 4; ++i) {
            int flat = i*256 + t;               // 64 l-pairs x 16 c4
            int lp = flat >> 4, c4l = flat & 15;
            float4 v0 = x4[(size_t)(2*lp)*32 + chalf*16 + c4l];
            float4 v1 = x4[(size_t)(2*lp + 1)*32 + chalf*16 + c4l];
            int lc = lp >> 2, lh = lp & 3;      // k-chunk, pair slot
            #pragma unroll
            for (int j0 = 0; j0 < 4; ++j0) {
                int j = (j0 + rot) & 3;
                int cl = c4l*4 + j;             // local channel row 0..63
                unsigned pk = pack2(((const float*)&v0)[j], ((const float*)&v1)[j]);
                *(unsigned*)&Als[((cl*16) + (lc ^ (cl & 7)))*8 + lh*2] = pk;
            }
        }
        stage_b128(Bls, WembT + kh*128, LL, t);
        __syncthreads();
        mfma_64x128(Als, Bls, acc, w, lane);
    }
    int mr = lane & 15, quad = lane >> 4;
    #pragma unroll
    for (int nf = 0; nf < 8; ++nf) {
        int f = nf*16 + mr;
        float bv = bias[f];
        #pragma unroll
        for (int r = 0; r < 4; ++r) {
            int node = chalf*64 + w*16 + quad*4 + r;
            hout[((size_t)b*CC + node)*HIDD + f] = (ushort)bfr(acc[nf][r] + bv);
        }
    }
}

// ---------------------------------------------------------------------------
// lin GEMM body (64-node tile): Als staged with 64 h rows; two B passes.
// ---------------------------------------------------------------------------
__device__ __forceinline__ void lin_body64(ushort* Als, ushort* Bls,
                                           const ushort* WlT, const ushort* WrT,
                                           const float* bl, const float* br,
                                           __half* xlT, __half* xrT,
                                           int b, int n0, int t) {
    int lane = t & 63, w = t >> 6;
    int mr = lane & 15, quad = lane >> 4;
    #pragma unroll
    for (int lr = 0; lr < 2; ++lr) {
        if (lr) __syncthreads();                     // Bls reuse guard
        stage_b128(Bls, lr ? WrT : WlT, HIDD, t);
        __syncthreads();
        f32x4 acc[8];
        ZERO_ACC8(acc)
        mfma_64x128(Als, Bls, acc, w, lane);
        const float* bias = lr ? br : bl;
        __half* out = lr ? xrT : xlT;
        #pragma unroll
        for (int nf = 0; nf < 8; ++nf) {
            int f = nf*16 + mr;
            float bv = bias[f];
            int h = f >> 5, d = f & 31;
            #pragma unroll
            for (int r = 0; r < 4; ++r) {
                int node = n0 + w*16 + quad*4 + r;
                out[(((size_t)b*HH + h)*CC + node)*DD + d] = __float2half(acc[nf][r] + bv);
            }
        }
    }
}

// ---------------------------------------------------------------------------
// K3: layer-0 lin, M-split: block (nhalf, b) handles 64 nodes. LDS 48KB.
// ---------------------------------------------------------------------------
__global__ __launch_bounds__(256) void lin_mfma(const ushort* __restrict__ hmat,
                                                const ushort* __restrict__ WlT,
                                                const ushort* __restrict__ WrT,
                                                const float* __restrict__ bl,
                                                const float* __restrict__ br,
                                                __half* __restrict__ xlT,
                                                __half* __restrict__ xrT) {
    __shared__ __align__(16) ushort Als[64*16*8];
    __shared__ __align__(16) ushort Bls[128*16*8];
    int n0 = blockIdx.x * 64, b = blockIdx.y;
    int t = threadIdx.x;
    stage_a64(Als, hmat + ((size_t)b*CC + n0)*HIDD, HIDD, t);
    lin_body64(Als, Bls, WlT, WrT, bl, br, xlT, xrT, b, n0, t);
}

// ---------------------------------------------------------------------------
// K3b: fused L0-epilogue + L1-lin, M-split: block (nhalf, b), 64 nodes.
// ---------------------------------------------------------------------------
__global__ __launch_bounds__(256) void epi_lin(const __half* __restrict__ xagg,
                                               const float* __restrict__ gbias,
                                               const float* __restrict__ ln_g,
                                               const float* __restrict__ ln_b,
                                               const float* __restrict__ Sg,
                                               const ushort* __restrict__ WlT,
                                               const ushort* __restrict__ WrT,
                                               const float* __restrict__ bl,
                                               const float* __restrict__ br,
                                               ushort* __restrict__ hmat,
                                               __half* __restrict__ xlT,
                                               __half* __restrict__ xrT) {
    __shared__ __align__(16) ushort Als[64*16*8];
    __shared__ __align__(16) ushort Bls[128*16*8];
    int n0 = blockIdx.x * 64, b = blockIdx.y;
    int t = threadIdx.x;
    epilogue64(xagg, gbias, ln_g, ln_b, Sg + (size_t)b*HH*CC, hmat, Als, b, n0, t, true);
    lin_body64(Als, Bls, WlT, WrT, bl, br, xlT, xrT, b, n0, t);
}

// ---------------------------------------------------------------------------
// K4: fused dense GATv2 attention (unchanged from R8/R10: two sequential dst
// passes, LDS split-overlay P-frag, unnormalized PV; Sg applied downstream).
// ---------------------------------------------------------------------------
#define SLOT(q, mr) ((mr)*4 + (((q) ^ (mr) ^ ((mr) >> 2)) & 3))

#define LOGIT_LOOP(FS)                                                        \
    pm0 = -3.0e38f; pm1 = -3.0e38f;                                           \
    _Pragma("unroll")                                                         \
    for (int j = 0; j < 32; ++j) {                                            \
        int src = sg*32 + j;                                                  \
        uint4 R[4];                                                           \
        const uint4* rpt = (const uint4*)&xl_lds[src*DD];                     \
        R[0]=rpt[0]; R[1]=rpt[1]; R[2]=rpt[2]; R[3]=rpt[3];                   \
        float sl = Slq[src];                                                  \
        const __half2* xv = (const __half2*)R;                                \
        __half2 a0 = __floats2half2_rn(0.f,0.f), a1 = a0, a2 = a0, a3 = a0;   \
        _Pragma("unroll")                                                     \
        for (int q = 0; q < 4; ++q) {                                         \
            a0 = __hfma2(qa2[4*q+0], __habs2(__hadd2(xv[4*q+0], xr2[4*q+0])), a0); \
            a1 = __hfma2(qa2[4*q+1], __habs2(__hadd2(xv[4*q+1], xr2[4*q+1])), a1); \
            a2 = __hfma2(qa2[4*q+2], __habs2(__hadd2(xv[4*q+2], xr2[4*q+2])), a2); \
            a3 = __hfma2(qa2[4*q+3], __habs2(__hadd2(xv[4*q+3], xr2[4*q+3])), a3); \
        }                                                                     \
        __half2 ts = __hadd2(__hadd2(a0, a1), __hadd2(a2, a3));               \
        float l = ((FS) + sl) + (__low2float(ts) + __high2float(ts));         \
        if (j & 1) { pm1 = fmaxf(pm1, l); lv[j >> 1] = __floats2half2_rn(lbuf, l); } \
        else       { pm0 = fmaxf(pm0, l); lbuf = l; }                         \
    }

#define EXP_PHASE(DST)                                                        \
    {                                                                         \
        float m_ = fmaxf(fmaxf(rp[0*CC + (DST)], rp[1*CC + (DST)]),           \
                         fmaxf(rp[2*CC + (DST)], rp[3*CC + (DST)]));          \
        uint4 M_[4];                                                          \
        const uint4* mp_ = (const uint4*)(mult_ds + (size_t)(DST)*CC + sg*32);\
        M_[0]=mp_[0]; M_[1]=mp_[1]; M_[2]=mp_[2]; M_[3]=mp_[3];               \
        const __half* mv_ = (const __half*)M_;                                \
        float s0_ = 0.f, s1_ = 0.f;                                           \
        _Pragma("unroll")                                                     \
        for (int i = 0; i < 16; ++i) {                                        \
            float e0 = __expf(__low2float(lv[i]) - m_) * __half2float(mv_[2*i]); \
            float e1 = __expf(__high2float(lv[i]) - m_) * __half2float(mv_[2*i+1]); \
            if (i & 1) s1_ += e0 + e1; else s0_ += e0 + e1;                   \
            lv[i] = __floats2half2_rn(e0, e1);                                \
        }                                                                     \
        sp[sg*CC + (DST)] = s0_ + s1_;                                        \
    }

#define WRITE_P(PF, DST)                                                      \
    {                                                                         \
        int mr_ = dl & 15, dr_ = dl >> 4;                                     \
        __half* pf_ = (PF) + ((size_t)(dr_*4 + sg)*64)*8;                     \
        _Pragma("unroll")                                                     \
        for (int q = 0; q < 4; ++q)                                           \
            *(uint4*)&pf_[SLOT(q, mr_)*8] = *(uint4*)&lv[q*4];                \
        if (Pg) {                                                             \
            __half* pg_ = Pg + (size_t)bh*CC*CC + (size_t)(DST)*CC + sg*32;   \
            _Pragma("unroll")                                                 \
            for (int q = 0; q < 4; ++q)                                       \
                *(uint4*)&pg_[q*8] = *(uint4*)&lv[q*4];                       \
        }                                                                     \
    }

__global__ __launch_bounds__(256)
void gat_fused(const __half* __restrict__ xl_h,
               const __half* __restrict__ xr_h,
               const __half* __restrict__ mult_ds,
               const float* __restrict__ att,
               __half* __restrict__ xagg,
               float* __restrict__ Sg,
               __half* __restrict__ Pg) {
    __shared__ __align__(16) __half smemA[CC*CC];      // 32KB split-overlay
    __shared__ __align__(16) __half xlT_swz[DD*16*8];  // 8KB  MFMA B (xor-swz)
    __half* xl_lds = smemA;                            // 8KB   (phase 1, lower)
    float*  Slq    = (float*)(smemA + CC*DD);          // 512B  (phase 1)
    float*  rp     = Slq + CC;                         // 2KB   (phase 1)
    float*  sp     = rp + 4*CC;                        // 2KB   (phase 1; ends 12.5K)
    __half* PfragA = smemA + 64*CC;                    // upper 16KB: rows 0..63
    __half* PfragB = smemA;                            // lower 16KB: rows 64..127

    int bh = blockIdx.x;
    int h = bh & 3, b = bh >> 2;
    int t = threadIdx.x;
    int sg = t >> 6, dl = t & 63;          // wave = src-group; lane = dst-local
    int dstA = dl, dstB = dl + 64;

    // stage xl slice (coalesced)
    {
        const uint4* spg = (const uint4*)(xl_h + (size_t)bh * CC * DD);
        uint4* dp = (uint4*)xl_lds;
        dp[t] = spg[t];
        dp[t + 256] = spg[t + 256];
    }
    // qa2 = 0.4*att (fp16 pairs)
    __half2 qa2[16];
    const float* ag = att + h*DD;
    #pragma unroll
    for (int c = 0; c < 8; ++c) {
        float4 av = *(const float4*)&ag[c*4];
        qa2[2*c+0] = __floats2half2_rn(0.4f*av.x, 0.4f*av.y);
        qa2[2*c+1] = __floats2half2_rn(0.4f*av.z, 0.4f*av.w);
    }
    // xr row for dstA only (pass A) + 1.5*Srq
    __half2 xr2[16];
    float fSA;
    {
        uint4 XA[4];
        const uint4* pa = (const uint4*)(xr_h + ((size_t)bh*CC + dstA)*DD);
        #pragma unroll
        for (int c = 0; c < 4; ++c) XA[c] = pa[c];
        const __half2* va = (const __half2*)XA;
        float sA = 0.f;
        #pragma unroll
        for (int i = 0; i < 16; ++i) {
            xr2[i] = va[i];
            __half2 p = __hmul2(qa2[i], xr2[i]);
            sA += __low2float(p) + __high2float(p);
        }
        fSA = 1.5f * sA;
    }
    __syncthreads();                                   // B0: xl staged

    // Slq[n] = 1.5 * sum_k 0.4*a_k*xl[n,k]   (threads 0..127)
    if (t < CC) {
        uint4 R[4];
        const uint4* rpt = (const uint4*)&xl_lds[t*DD];
        #pragma unroll
        for (int c = 0; c < 4; ++c) R[c] = rpt[c];
        const __half2* rv = (const __half2*)R;
        __half2 s = __floats2half2_rn(0.f, 0.f);
        #pragma unroll
        for (int i = 0; i < 16; ++i) s = __hfma2(qa2[i], rv[i], s);
        Slq[t] = 1.5f * (__low2float(s) + __high2float(s));
    }
    // build transposed+swizzled xl for MFMA B operand
    for (int i = t; i < 512; i += 256) {
        int f = i & 31, c = i >> 5;
        __align__(16) __half v[8];
        #pragma unroll
        for (int e = 0; e < 8; ++e) v[e] = xl_lds[(c*8 + e)*DD + f];
        *(uint4*)&xlT_swz[((f*16) + (c ^ (f & 7)))*8] = *(uint4*)v;
    }
    __syncthreads();                                   // B1: Slq/swz ready

    __align__(16) __half2 lv[16];
    float pm0, pm1, lbuf = 0.f;

    // ---- PASS A: dstA = dl ----
    LOGIT_LOOP(fSA)
    rp[sg*CC + dstA] = fmaxf(pm0, pm1);
    __syncthreads();                                   // B2: rp[A] ready
    EXP_PHASE(dstA)
    WRITE_P(PfragA, dstA)                              // upper region: no hazard

    // ---- load xr for dstB (xrA dead) ----
    float fSB;
    {
        uint4 XB[4];
        const uint4* pb = (const uint4*)(xr_h + ((size_t)bh*CC + dstB)*DD);
        #pragma unroll
        for (int c = 0; c < 4; ++c) XB[c] = pb[c];
        const __half2* vb = (const __half2*)XB;
        float sB = 0.f;
        #pragma unroll
        for (int i = 0; i < 16; ++i) {
            xr2[i] = vb[i];
            __half2 p = __hmul2(qa2[i], xr2[i]);
            sB += __low2float(p) + __high2float(p);
        }
        fSB = 1.5f * sB;
    }

    // ---- PASS B: dstB = dl + 64 (rp/sp slots disjoint from A's) ----
    LOGIT_LOOP(fSB)
    rp[sg*CC + dstB] = fmaxf(pm0, pm1);
    __syncthreads();                                   // B3: rp[B] ready
    EXP_PHASE(dstB)
    __syncthreads();                                   // B4: sp[A]+sp[B] ready

    // row inverse-sums -> Sg (sg==0 only)
    if (sg == 0) {
        float isA = 1.f / (((sp[0*CC + dstA] + sp[1*CC + dstA]) +
                            (sp[2*CC + dstA] + sp[3*CC + dstA])) + 1e-16f);
        float isB = 1.f / (((sp[0*CC + dstB] + sp[1*CC + dstB]) +
                            (sp[2*CC + dstB] + sp[3*CC + dstB])) + 1e-16f);
        Sg[(size_t)bh*CC + dstA] = isA;
        Sg[(size_t)bh*CC + dstB] = isB;
    }
    __syncthreads();                                   // B5: sp reads done -> overlay OK
    WRITE_P(PfragB, dstB)                              // lower region (over dead xl)
    __syncthreads();                                   // B6: P complete

    // ---- PV on MFMA: wave sg owns rows sg*32..+31; output UNNORMALIZED ----
    int quad = dl >> 4, mr = dl & 15;
    f16x8 afr[2][4];
    #pragma unroll
    for (int mf = 0; mf < 2; ++mf) {
        int dr0 = sg*2 + mf;                           // global row>>4
        const __half* base = (dr0 < 4) ? PfragA : PfragB;
        int drl = dr0 & 3;
        #pragma unroll
        for (int ks = 0; ks < 4; ++ks)
            afr[mf][ks] = *(const f16x8*)&base[((drl*4 + ks)*64 + SLOT(quad, mr))*8];
    }
    f32x4 acc[2][2];
    #pragma unroll
    for (int i = 0; i < 2; ++i)
        #pragma unroll
        for (int j = 0; j < 2; ++j) acc[i][j] = (f32x4){0.f,0.f,0.f,0.f};
    #pragma unroll
    for (int ks = 0; ks < 4; ++ks) {
        int ca = ks*4 + quad;
        f16x8 bfr2[2];
        #pragma unroll
        for (int nf = 0; nf < 2; ++nf) {
            int n = nf*16 + mr;
            bfr2[nf] = *(const f16x8*)&xlT_swz[((n*16) + (ca ^ (n & 7)))*8];
        }
        #pragma unroll
        for (int mf = 0; mf < 2; ++mf)
            #pragma unroll
            for (int nf = 0; nf < 2; ++nf)
                acc[mf][nf] = __builtin_amdgcn_mfma_f32_16x16x32_f16(afr[mf][ks], bfr2[nf], acc[mf][nf], 0, 0, 0);
    }
    #pragma unroll
    for (int mf = 0; mf < 2; ++mf)
        #pragma unroll
        for (int nf = 0; nf < 2; ++nf) {
            int f = nf*16 + mr;
            #pragma unroll
            for (int r = 0; r < 4; ++r) {
                int node = sg*32 + mf*16 + quad*4 + r;
                xagg[(((size_t)b*CC + node)*HH + h)*DD + f] = __float2half(acc[mf][nf][r]);
            }
        }
}

// ---------------------------------------------------------------------------
// K6: fused L1-epilogue + attention-map + projection GEMM, M-split over l:
// block (lhalf, b) computes 128 l-rows x 128 c. Both halves rebuild the h
// tile (cheap); attn-map gated to lhalf==0. LDS 64KB -> 2 blocks/CU.
// ---------------------------------------------------------------------------
__global__ __launch_bounds__(256) void epi_proj(const __half* __restrict__ xagg,
                                                const float* __restrict__ gbias,
                                                const float* __restrict__ ln_g,
                                                const float* __restrict__ ln_b,
                                                const float* __restrict__ Sg,
                                                const __half* __restrict__ Pg,
                                                const ushort* __restrict__ WpT,
                                                const float* __restrict__ pbias,
                                                const ushort* __restrict__ hmat,
                                                float* __restrict__ out,
                                                float* __restrict__ attn_out) {
    __shared__ __align__(16) ushort Als[128*16*8];
    __shared__ __align__(16) ushort Bls[128*16*8];
    int lhalf = blockIdx.x, b = blockIdx.y;
    int t = threadIdx.x;
    const float* Sg_b = Sg + (size_t)b*HH*CC;
    epilogue128(xagg, gbias, ln_g, ln_b, Sg_b, hmat, Bls, b, t);

    // attention map rows (lhalf 0 only): attn[node][src] = 0.25*sum_h p*is
    if (lhalf == 0) {
        int nl = t >> 1, fh = t & 1;
        int node = b*CC + nl;
        float ish[HH];
        #pragma unroll
        for (int hh = 0; hh < HH; ++hh) ish[hh] = Sg_b[hh*CC + nl];
        #pragma unroll
        for (int c = 0; c < 8; ++c) {
            float a[8] = {0.f,0.f,0.f,0.f,0.f,0.f,0.f,0.f};
            #pragma unroll
            for (int hh = 0; hh < HH; ++hh) {
                uint4 pu = *(const uint4*)&Pg[((size_t)(b*HH + hh)*CC + nl)*CC + fh*64 + c*8];
                const __half2* pv = (const __half2*)&pu;
                #pragma unroll
                for (int i = 0; i < 4; ++i) {
                    a[2*i]   += __low2float(pv[i]) * ish[hh];
                    a[2*i+1] += __high2float(pv[i]) * ish[hh];
                }
            }
            float4 o0, o1;
            o0.x = 0.25f*a[0]; o0.y = 0.25f*a[1]; o0.z = 0.25f*a[2]; o0.w = 0.25f*a[3];
            o1.x = 0.25f*a[4]; o1.y = 0.25f*a[5]; o1.z = 0.25f*a[6]; o1.w = 0.25f*a[7];
            *(float4*)&attn_out[(size_t)node*CC + fh*64 + c*8]     = o0;
            *(float4*)&attn_out[(size_t)node*CC + fh*64 + c*8 + 4] = o1;
        }
    }

    int lane = t & 63, w = t >> 6;
    int mr = lane & 15, quad = lane >> 4;
    stage_b128(Als, WpT + (size_t)lhalf*128*HIDD, HIDD, t);
    __syncthreads();
    f32x4 acc[2][8];
    ZERO_ACC28(acc)
    mfma_tile_128(Als, Bls, acc, w, lane);
    #pragma unroll
    for (int nf = 0; nf < 8; ++nf) {
        int c = nf*16 + mr;
        #pragma unroll
        for (int mf = 0; mf < 2; ++mf)
            #pragma unroll
            for (int r = 0; r < 4; ++r) {
                int l = lhalf*128 + w*32 + mf*16 + quad*4 + r;
                out[((size_t)b*LL + l)*CC + c] = acc[mf][nf][r] + pbias[l];
            }
    }
}

// ---------------------------------------------------------------------------
extern "C" void kernel_launch(void* const* d_in, const int* in_sizes, int n_in,
                              void* d_out, int out_size, void* d_ws, size_t ws_size,
                              hipStream_t stream) {
    const float* x        = (const float*)d_in[0];
    const int*   edge     = (const int*)d_in[1];
    const float* emb_W    = (const float*)d_in[2];
    const float* emb_b    = (const float*)d_in[3];
    const float* lin_l_W  = (const float*)d_in[4];
    const float* lin_l_b  = (const float*)d_in[5];
    const float* lin_r_W  = (const float*)d_in[6];
    const float* lin_r_b  = (const float*)d_in[7];
    const float* att      = (const float*)d_in[8];
    const float* gat_bias = (const float*)d_in[9];
    const float* ln_g     = (const float*)d_in[10];
    const float* ln_b     = (const float*)d_in[11];
    const float* proj_W   = (const float*)d_in[12];
    const float* proj_b   = (const float*)d_in[13];

    // workspace: h(bf16) | xl | xr | xagg | Pg | mult | Sg | W
    ushort* h     = (ushort*)d_ws;
    __half* xl_h  = (__half*)(h + (size_t)NN * HIDD);
    __half* xr_h  = xl_h + (size_t)NN * HIDD;
    __half* xagg  = xr_h + (size_t)NN * HIDD;
    __half* Pg    = xagg + (size_t)NN * HIDD;
    __half* mult_ds = Pg + (size_t)BB * HH * CC * CC;
    float*  Sg    = (float*)(mult_ds + (size_t)CC * CC);
    ushort* WembT = (ushort*)(Sg + (size_t)BB * HH * CC);
    ushort* WlrT  = WembT + (size_t)CC*LL;
    ushort* WpT   = WlrT + (size_t)4*HIDD*HIDD;

    float* out0 = (float*)d_out;                       // (B, L, C)
    float* attn = out0 + (size_t)BB * LL * CC;         // (B, C, C)

    prep_weights<<<65, 256, 0, stream>>>(emb_W, lin_l_W, lin_r_W, proj_W, edge,
                                         WembT, WlrT, WpT, mult_ds);
    embed_mfma<<<dim3(2, BB), 256, 0, stream>>>(x, WembT, emb_b, h);
    lin_mfma<<<dim3(2, BB), 256, 0, stream>>>(h, WlrT, WlrT + (size_t)HIDD*HIDD,
                                              lin_l_b, lin_r_b, xl_h, xr_h);
    gat_fused<<<BB*HH, 256, 0, stream>>>(xl_h, xr_h, mult_ds, att, xagg, Sg, nullptr);
    epi_lin<<<dim3(2, BB), 256, 0, stream>>>(xagg, gat_bias, ln_g, ln_b, Sg,
                                             WlrT + (size_t)2*HIDD*HIDD,
                                             WlrT + (size_t)3*HIDD*HIDD,
                                             lin_l_b + HIDD, lin_r_b + HIDD,
                                             h, xl_h, xr_h);
    gat_fused<<<BB*HH, 256, 0, stream>>>(xl_h, xr_h, mult_ds, att + HIDD, xagg, Sg, Pg);
    epi_proj<<<dim3(2, BB), 256, 0, stream>>>(xagg, gat_bias + HIDD, ln_g + HIDD, ln_b + HIDD,
                                              Sg, Pg, WpT, proj_b, h, out0, attn);
}

// Round 12
// 267.021 us; speedup vs baseline: 1.1458x; 1.1458x over previous
//
#include <hip/hip_runtime.h>
#include <hip/hip_fp16.h>
#include <math.h>

// Problem constants
#define BB 256
#define LL 256
#define CC 128
#define HIDD 128
#define HH 4
#define DD 32
#define EE 4096
#define NN (BB*CC)          // 32768 nodes
#define LN_EPS 1e-5f

typedef short bf16x8 __attribute__((ext_vector_type(8)));
typedef _Float16 f16x8 __attribute__((ext_vector_type(8)));
typedef float f32x4 __attribute__((ext_vector_type(4)));

// ---------------------------------------------------------------------------
// helpers
// ---------------------------------------------------------------------------
__device__ __forceinline__ unsigned bfr(float f) {        // fp32 -> bf16 bits, RNE
    unsigned x = __float_as_uint(f);
    return (x + 0x7FFFu + ((x >> 16) & 1u)) >> 16;
}
__device__ __forceinline__ unsigned pack2(float a, float b) { return bfr(a) | (bfr(b) << 16); }
__device__ __forceinline__ float b2f(unsigned u) { return __uint_as_float(u << 16); }

// ---------------------------------------------------------------------------
// MFMA GEMM building blocks, 512-thread (8-wave) variants (R10 best config).
// LDS tile: 128 rows x 16 chunks (16B), physical chunk = c ^ (row&7).
// ---------------------------------------------------------------------------
__device__ __forceinline__ void stage_bf16_rm512(ushort* lds, const ushort* src, int ldm, int t) {
    #pragma unroll
    for (int i = 0; i < 4; ++i) {
        int flat = i*512 + t;
        int r = flat >> 4, c = flat & 15;
        uint4 pk = *(const uint4*)(src + (size_t)r*ldm + c*8);
        *(uint4*)&lds[((r*16) + (c ^ (r & 7)))*8] = pk;
    }
}
// wave w: rows w*16..w*16+15, all 128 cols (1 m-frag x 8 n-frags)
__device__ __forceinline__ void mfma_tile_512(const ushort* Als, const ushort* Bls,
                                              f32x4 acc[8], int w, int lane) {
    int mr = lane & 15, quad = lane >> 4;
    int m = w*16 + mr;
    #pragma unroll
    for (int ks = 0; ks < 4; ++ks) {
        int ca = ks*4 + quad;
        bf16x8 a = *(const bf16x8*)&Als[((m*16) + (ca ^ (m & 7)))*8];
        bf16x8 b[8];
        #pragma unroll
        for (int nf = 0; nf < 8; ++nf) {
            int n = nf*16 + mr;
            b[nf] = *(const bf16x8*)&Bls[((n*16) + (ca ^ (n & 7)))*8];
        }
        #pragma unroll
        for (int nf = 0; nf < 8; ++nf)
            acc[nf] = __builtin_amdgcn_mfma_f32_16x16x32_bf16(a, b[nf], acc[nf], 0, 0, 0);
    }
}
#define ZERO_ACC8(acc) { _Pragma("unroll") for (int j_=0;j_<8;++j_) acc[j_] = (f32x4){0.f,0.f,0.f,0.f}; }

// ---------------------------------------------------------------------------
// Fused epilogue phase (512-thread): 4 threads per node (nl = t>>2, fq = t&3),
// each owns 32 features (= one head). NORMALIZE xagg by Sg inverse row-sum,
// bias -> ELU -> residual -> LayerNorm (4-lane shfl reduce), stage bf16 rows
// into an LDS GEMM tile (swizzled), optionally write h.
// ---------------------------------------------------------------------------
__device__ __forceinline__ void epilogue_to_tile512(const __half* __restrict__ xagg,
                                                    const float* __restrict__ gbias,
                                                    const float* __restrict__ ln_g,
                                                    const float* __restrict__ ln_b,
                                                    const float* __restrict__ Sg_b,
                                                    ushort* __restrict__ hmat,
                                                    ushort* __restrict__ tile,
                                                    int b, int t, bool write_h) {
    int nl = t >> 2, fq = t & 3;
    int node = b*CC + nl;
    const __half* xa = xagg + (size_t)node*HIDD + fq*32;
    ushort* hp = hmat + (size_t)node*HIDD + fq*32;
    const float* gb = gbias + fq*32;
    float isv = Sg_b[fq*CC + nl];

    __half2 hv[16];
    float sum = 0.f;
    #pragma unroll
    for (int c = 0; c < 4; ++c) {
        uint4 xu = *(const uint4*)&xa[c*8];
        uint4 hu = *(const uint4*)&hp[c*8];
        const __half2* xp2 = (const __half2*)&xu;
        const ushort* hs = (const ushort*)&hu;
        float gv[8];
        *(float4*)&gv[0] = *(const float4*)&gb[c*8];
        *(float4*)&gv[4] = *(const float4*)&gb[c*8 + 4];
        #pragma unroll
        for (int i = 0; i < 4; ++i) {
            float o0 = __low2float(xp2[i]) * isv + gv[2*i];
            float o1 = __high2float(xp2[i]) * isv + gv[2*i+1];
            o0 = o0 > 0.f ? o0 : (__expf(o0) - 1.f);
            o1 = o1 > 0.f ? o1 : (__expf(o1) - 1.f);
            float v0 = b2f((unsigned)hs[2*i]) + o0;
            float v1 = b2f((unsigned)hs[2*i+1]) + o1;
            sum += v0 + v1;
            hv[c*4 + i] = __floats2half2_rn(v0, v1);
        }
    }
    sum += __shfl_xor(sum, 1);
    sum += __shfl_xor(sum, 2);
    float mean = sum * 0.0078125f;
    float q = 0.f;
    #pragma unroll
    for (int i = 0; i < 16; ++i) {
        float d0 = __low2float(hv[i]) - mean;
        float d1 = __high2float(hv[i]) - mean;
        q += d0*d0 + d1*d1;
    }
    q += __shfl_xor(q, 1);
    q += __shfl_xor(q, 2);
    float var = q * 0.0078125f;
    float rs = rsqrtf(var + LN_EPS);
    const float* lg = ln_g + fq*32;
    const float* lb = ln_b + fq*32;
    #pragma unroll
    for (int c = 0; c < 4; ++c) {
        float gv[8], bv[8];
        *(float4*)&gv[0] = *(const float4*)&lg[c*8];
        *(float4*)&gv[4] = *(const float4*)&lg[c*8 + 4];
        *(float4*)&bv[0] = *(const float4*)&lb[c*8];
        *(float4*)&bv[4] = *(const float4*)&lb[c*8 + 4];
        __align__(16) ushort ov[8];
        #pragma unroll
        for (int i = 0; i < 4; ++i) {
            float d0 = __low2float(hv[c*4 + i]) - mean;
            float d1 = __high2float(hv[c*4 + i]) - mean;
            ov[2*i]   = (ushort)bfr(d0*rs*gv[2*i]   + bv[2*i]);
            ov[2*i+1] = (ushort)bfr(d1*rs*gv[2*i+1] + bv[2*i+1]);
        }
        int cg = fq*4 + c;
        *(uint4*)&tile[((nl*16) + (cg ^ (nl & 7)))*8] = *(uint4*)ov;
        if (write_h) *(uint4*)&hp[c*8] = *(uint4*)ov;
    }
}

// ---------------------------------------------------------------------------
// K0: weight prep (blocks 0..63) + dense multiplicity table (block 64).
// mult[dst][src] = #edges(src,dst) (+1 on diagonal), fp16.
// p = exp(l - rowmax) * mult reproduces the segment softmax exactly.
// ---------------------------------------------------------------------------
__global__ __launch_bounds__(256) void prep_weights(const float* __restrict__ emb_W,
                                                    const float* __restrict__ lWl,
                                                    const float* __restrict__ lWr,
                                                    const float* __restrict__ pW,
                                                    const int* __restrict__ edge,
                                                    ushort* __restrict__ WembT,
                                                    ushort* __restrict__ WlrT,
                                                    ushort* __restrict__ WpT,
                                                    __half* __restrict__ mult_ds) {
    __shared__ int cnt[CC*CC];              // 64KB (used by block 64 only)
    int t = threadIdx.x;
    if (blockIdx.x == 64) {
        for (int i = t; i < CC*CC; i += 256) cnt[i] = 0;
        __syncthreads();
        for (int j = t; j < EE; j += 256) {
            int s = edge[j], d = edge[EE + j];
            atomicAdd(&cnt[s*CC + d], 1);
        }
        __syncthreads();
        for (int o = t; o < CC*CC; o += 256) {
            int dstc = o >> 7, srcc = o & 127;
            int c = cnt[srcc*CC + dstc] + ((srcc == dstc) ? 1 : 0);
            mult_ds[o] = __float2half((float)c);
        }
        return;
    }
    int gid = blockIdx.x * 256 + t;
    float v[8];
    if (gid < 4096) {                       // emb: 128 f x 32 l-chunks
        int f = gid >> 5, ch = gid & 31;
        #pragma unroll
        for (int j = 0; j < 8; ++j) v[j] = emb_W[(size_t)(ch*8 + j)*HIDD + f];
        uint4 pk; pk.x = pack2(v[0],v[1]); pk.y = pack2(v[2],v[3]);
        pk.z = pack2(v[4],v[5]); pk.w = pack2(v[6],v[7]);
        *(uint4*)&WembT[(size_t)f*LL + ch*8] = pk;
    } else if (gid < 12288) {               // lin: 4 mats x 128 f x 16 k-chunks
        int g = gid - 4096;
        int mat = g >> 11, f = (g >> 4) & 127, ch = g & 15;
        const float* src = ((mat & 1) ? lWr : lWl) + (size_t)(mat >> 1)*HIDD*HIDD;
        #pragma unroll
        for (int j = 0; j < 8; ++j) v[j] = src[(size_t)(ch*8 + j)*HIDD + f];
        uint4 pk; pk.x = pack2(v[0],v[1]); pk.y = pack2(v[2],v[3]);
        pk.z = pack2(v[4],v[5]); pk.w = pack2(v[6],v[7]);
        *(uint4*)&WlrT[(size_t)mat*HIDD*HIDD + (size_t)f*HIDD + ch*8] = pk;
    } else {                                // proj: 256 l x 16 k-chunks
        int g = gid - 12288;
        int l = g >> 4, ch = g & 15;
        #pragma unroll
        for (int j = 0; j < 8; ++j) v[j] = pW[(size_t)(ch*8 + j)*LL + l];
        uint4 pk; pk.x = pack2(v[0],v[1]); pk.y = pack2(v[2],v[3]);
        pk.z = pack2(v[4],v[5]); pk.w = pack2(v[6],v[7]);
        *(uint4*)&WpT[(size_t)l*HIDD + ch*8] = pk;
    }
}

// ---------------------------------------------------------------------------
// lin GEMM body (512 threads): Als staged with h rows; two B passes (Wl, Wr),
// fp16 outputs in xlT/xrT head-sliced layout.
// ---------------------------------------------------------------------------
__device__ __forceinline__ void lin_body512(ushort* Als, ushort* Bls,
                                            const ushort* WlT, const ushort* WrT,
                                            const float* bl, const float* br,
                                            __half* xlT, __half* xrT, int b, int t) {
    int lane = t & 63, w = t >> 6;
    int mr = lane & 15, quad = lane >> 4;
    #pragma unroll
    for (int lr = 0; lr < 2; ++lr) {
        if (lr) __syncthreads();                     // Bls reuse guard
        stage_bf16_rm512(Bls, lr ? WrT : WlT, HIDD, t);
        __syncthreads();
        f32x4 acc[8];
        ZERO_ACC8(acc)
        mfma_tile_512(Als, Bls, acc, w, lane);
        const float* bias = lr ? br : bl;
        __half* out = lr ? xrT : xlT;
        #pragma unroll
        for (int nf = 0; nf < 8; ++nf) {
            int f = nf*16 + mr;
            float bv = bias[f];
            int h = f >> 5, d = f & 31;
            #pragma unroll
            for (int r = 0; r < 4; ++r) {
                int node = w*16 + quad*4 + r;
                out[(((size_t)b*HH + h)*CC + node)*DD + d] = __float2half(acc[nf][r] + bv);
            }
        }
    }
}

// ---------------------------------------------------------------------------
// K2: FUSED embed GEMM + L0 lin GEMM (512 threads, one block per b).
// Embed: x-transpose staged -> MFMA -> bias. h written to global AND
// forwarded into the lin A-tile through LDS (no global h re-read, no
// inter-kernel launch gap). Then the two lin B-passes run immediately.
// Tests the inter-kernel-overhead hypothesis: launches 7 -> 6.
// ---------------------------------------------------------------------------
__global__ __launch_bounds__(512) void embed_lin(const float* __restrict__ x,
                                                 const ushort* __restrict__ WembT,
                                                 const float* __restrict__ emb_bias,
                                                 const ushort* __restrict__ WlT,
                                                 const ushort* __restrict__ WrT,
                                                 const float* __restrict__ bl,
                                                 const float* __restrict__ br,
                                                 ushort* __restrict__ hout,
                                                 __half* __restrict__ xlT,
                                                 __half* __restrict__ xrT) {
    __shared__ __align__(16) ushort Als[128*16*8];    // x-tile, then h-tile
    __shared__ __align__(16) ushort Bls[128*16*8];    // Wemb, then Wl/Wr
    int b = blockIdx.x;
    int t = threadIdx.x, lane = t & 63, w = t >> 6;
    f32x4 acc[8];
    ZERO_ACC8(acc)
    #pragma unroll
    for (int kh = 0; kh < 2; ++kh) {
        if (kh) __syncthreads();
        const float4* x4 = (const float4*)(x + (size_t)b*LL*CC + (size_t)kh*128*CC);
        int rot = (t >> 3) & 3;
        #pragma unroll
        for (int i = 0; i < 4; ++i) {
            int flat = i*512 + t;               // 0..2047  (row-pairs x 32 f4)
            int lp = flat >> 5, c4 = flat & 31; // l = 2lp, 2lp+1
            float4 v0 = x4[(size_t)(2*lp)*32 + c4];
            float4 v1 = x4[(size_t)(2*lp + 1)*32 + c4];
            int lc = lp >> 2, lh = lp & 3;      // k-chunk, half-pair slot
            #pragma unroll
            for (int j0 = 0; j0 < 4; ++j0) {
                int j = (j0 + rot) & 3;
                int c = c4*4 + j;
                unsigned pk = pack2(((const float*)&v0)[j], ((const float*)&v1)[j]);
                *(unsigned*)&Als[((c*16) + (lc ^ (c & 7)))*8 + lh*2] = pk;
            }
        }
        stage_bf16_rm512(Bls, WembT + kh*128, LL, t);
        __syncthreads();
        mfma_tile_512(Als, Bls, acc, w, lane);
    }
    __syncthreads();                        // embed MFMAs done -> Als/Bls free
    // bias + write h (global) + forward h into Als tile (swizzled layout)
    {
        int mr = lane & 15, quad = lane >> 4;
        #pragma unroll
        for (int nf = 0; nf < 8; ++nf) {
            int f = nf*16 + mr;
            float bv = emb_bias[f];
            int chunk = nf*2 + (mr >> 3), elem = mr & 7;
            #pragma unroll
            for (int r = 0; r < 4; ++r) {
                int node = w*16 + quad*4 + r;
                ushort hv = (ushort)bfr(acc[nf][r] + bv);
                hout[((size_t)b*CC + node)*HIDD + f] = hv;
                Als[((node*16) + (chunk ^ (node & 7)))*8 + elem] = hv;
            }
        }
    }
    __syncthreads();                        // h-tile complete
    lin_body512(Als, Bls, WlT, WrT, bl, br, xlT, xrT, b, t);
}

// ---------------------------------------------------------------------------
// K3b: fused L0-epilogue + L1-lin (512 threads). LN output staged straight
// into Als and written once to h (needed for the L1 residual).
// ---------------------------------------------------------------------------
__global__ __launch_bounds__(512) void epi_lin(const __half* __restrict__ xagg,
                                               const float* __restrict__ gbias,
                                               const float* __restrict__ ln_g,
                                               const float* __restrict__ ln_b,
                                               const float* __restrict__ Sg,
                                               const ushort* __restrict__ WlT,
                                               const ushort* __restrict__ WrT,
                                               const float* __restrict__ bl,
                                               const float* __restrict__ br,
                                               ushort* __restrict__ hmat,
                                               __half* __restrict__ xlT,
                                               __half* __restrict__ xrT) {
    __shared__ __align__(16) ushort Als[128*16*8];
    __shared__ __align__(16) ushort Bls[128*16*8];
    int b = blockIdx.x, t = threadIdx.x;
    epilogue_to_tile512(xagg, gbias, ln_g, ln_b, Sg + (size_t)b*HH*CC, hmat, Als, b, t, true);
    lin_body512(Als, Bls, WlT, WrT, bl, br, xlT, xrT, b, t);
}

// ---------------------------------------------------------------------------
// K4: fused dense GATv2 attention (unchanged from R8/R10: two sequential dst
// passes, LDS split-overlay P-frag, unnormalized PV; Sg applied downstream).
// ---------------------------------------------------------------------------
#define SLOT(q, mr) ((mr)*4 + (((q) ^ (mr) ^ ((mr) >> 2)) & 3))

#define LOGIT_LOOP(FS)                                                        \
    pm0 = -3.0e38f; pm1 = -3.0e38f;                                           \
    _Pragma("unroll")                                                         \
    for (int j = 0; j < 32; ++j) {                                            \
        int src = sg*32 + j;                                                  \
        uint4 R[4];                                                           \
        const uint4* rpt = (const uint4*)&xl_lds[src*DD];                     \
        R[0]=rpt[0]; R[1]=rpt[1]; R[2]=rpt[2]; R[3]=rpt[3];                   \
        float sl = Slq[src];                                                  \
        const __half2* xv = (const __half2*)R;                                \
        __half2 a0 = __floats2half2_rn(0.f,0.f), a1 = a0, a2 = a0, a3 = a0;   \
        _Pragma("unroll")                                                     \
        for (int q = 0; q < 4; ++q) {                                         \
            a0 = __hfma2(qa2[4*q+0], __habs2(__hadd2(xv[4*q+0], xr2[4*q+0])), a0); \
            a1 = __hfma2(qa2[4*q+1], __habs2(__hadd2(xv[4*q+1], xr2[4*q+1])), a1); \
            a2 = __hfma2(qa2[4*q+2], __habs2(__hadd2(xv[4*q+2], xr2[4*q+2])), a2); \
            a3 = __hfma2(qa2[4*q+3], __habs2(__hadd2(xv[4*q+3], xr2[4*q+3])), a3); \
        }                                                                     \
        __half2 ts = __hadd2(__hadd2(a0, a1), __hadd2(a2, a3));               \
        float l = ((FS) + sl) + (__low2float(ts) + __high2float(ts));         \
        if (j & 1) { pm1 = fmaxf(pm1, l); lv[j >> 1] = __floats2half2_rn(lbuf, l); } \
        else       { pm0 = fmaxf(pm0, l); lbuf = l; }                         \
    }

#define EXP_PHASE(DST)                                                        \
    {                                                                         \
        float m_ = fmaxf(fmaxf(rp[0*CC + (DST)], rp[1*CC + (DST)]),           \
                         fmaxf(rp[2*CC + (DST)], rp[3*CC + (DST)]));          \
        uint4 M_[4];                                                          \
        const uint4* mp_ = (const uint4*)(mult_ds + (size_t)(DST)*CC + sg*32);\
        M_[0]=mp_[0]; M_[1]=mp_[1]; M_[2]=mp_[2]; M_[3]=mp_[3];               \
        const __half* mv_ = (const __half*)M_;                                \
        float s0_ = 0.f, s1_ = 0.f;                                           \
        _Pragma("unroll")                                                     \
        for (int i = 0; i < 16; ++i) {                                        \
            float e0 = __expf(__low2float(lv[i]) - m_) * __half2float(mv_[2*i]); \
            float e1 = __expf(__high2float(lv[i]) - m_) * __half2float(mv_[2*i+1]); \
            if (i & 1) s1_ += e0 + e1; else s0_ += e0 + e1;                   \
            lv[i] = __floats2half2_rn(e0, e1);                                \
        }                                                                     \
        sp[sg*CC + (DST)] = s0_ + s1_;                                        \
    }

#define WRITE_P(PF, DST)                                                      \
    {                                                                         \
        int mr_ = dl & 15, dr_ = dl >> 4;                                     \
        __half* pf_ = (PF) + ((size_t)(dr_*4 + sg)*64)*8;                     \
        _Pragma("unroll")                                                     \
        for (int q = 0; q < 4; ++q)                                           \
            *(uint4*)&pf_[SLOT(q, mr_)*8] = *(uint4*)&lv[q*4];                \
        if (Pg) {                                                             \
            __half* pg_ = Pg + (size_t)bh*CC*CC + (size_t)(DST)*CC + sg*32;   \
            _Pragma("unroll")                                                 \
            for (int q = 0; q < 4; ++q)                                       \
                *(uint4*)&pg_[q*8] = *(uint4*)&lv[q*4];                       \
        }                                                                     \
    }

__global__ __launch_bounds__(256)
void gat_fused(const __half* __restrict__ xl_h,
               const __half* __restrict__ xr_h,
               const __half* __restrict__ mult_ds,
               const float* __restrict__ att,
               __half* __restrict__ xagg,
               float* __restrict__ Sg,
               __half* __restrict__ Pg) {
    __shared__ __align__(16) __half smemA[CC*CC];      // 32KB split-overlay
    __shared__ __align__(16) __half xlT_swz[DD*16*8];  // 8KB  MFMA B (xor-swz)
    __half* xl_lds = smemA;                            // 8KB   (phase 1, lower)
    float*  Slq    = (float*)(smemA + CC*DD);          // 512B  (phase 1)
    float*  rp     = Slq + CC;                         // 2KB   (phase 1)
    float*  sp     = rp + 4*CC;                        // 2KB   (phase 1; ends 12.5K)
    __half* PfragA = smemA + 64*CC;                    // upper 16KB: rows 0..63
    __half* PfragB = smemA;                            // lower 16KB: rows 64..127

    int bh = blockIdx.x;
    int h = bh & 3, b = bh >> 2;
    int t = threadIdx.x;
    int sg = t >> 6, dl = t & 63;          // wave = src-group; lane = dst-local
    int dstA = dl, dstB = dl + 64;

    // stage xl slice (coalesced)
    {
        const uint4* spg = (const uint4*)(xl_h + (size_t)bh * CC * DD);
        uint4* dp = (uint4*)xl_lds;
        dp[t] = spg[t];
        dp[t + 256] = spg[t + 256];
    }
    // qa2 = 0.4*att (fp16 pairs)
    __half2 qa2[16];
    const float* ag = att + h*DD;
    #pragma unroll
    for (int c = 0; c < 8; ++c) {
        float4 av = *(const float4*)&ag[c*4];
        qa2[2*c+0] = __floats2half2_rn(0.4f*av.x, 0.4f*av.y);
        qa2[2*c+1] = __floats2half2_rn(0.4f*av.z, 0.4f*av.w);
    }
    // xr row for dstA only (pass A) + 1.5*Srq
    __half2 xr2[16];
    float fSA;
    {
        uint4 XA[4];
        const uint4* pa = (const uint4*)(xr_h + ((size_t)bh*CC + dstA)*DD);
        #pragma unroll
        for (int c = 0; c < 4; ++c) XA[c] = pa[c];
        const __half2* va = (const __half2*)XA;
        float sA = 0.f;
        #pragma unroll
        for (int i = 0; i < 16; ++i) {
            xr2[i] = va[i];
            __half2 p = __hmul2(qa2[i], xr2[i]);
            sA += __low2float(p) + __high2float(p);
        }
        fSA = 1.5f * sA;
    }
    __syncthreads();                                   // B0: xl staged

    // Slq[n] = 1.5 * sum_k 0.4*a_k*xl[n,k]   (threads 0..127)
    if (t < CC) {
        uint4 R[4];
        const uint4* rpt = (const uint4*)&xl_lds[t*DD];
        #pragma unroll
        for (int c = 0; c < 4; ++c) R[c] = rpt[c];
        const __half2* rv = (const __half2*)R;
        __half2 s = __floats2half2_rn(0.f, 0.f);
        #pragma unroll
        for (int i = 0; i < 16; ++i) s = __hfma2(qa2[i], rv[i], s);
        Slq[t] = 1.5f * (__low2float(s) + __high2float(s));
    }
    // build transposed+swizzled xl for MFMA B operand
    for (int i = t; i < 512; i += 256) {
        int f = i & 31, c = i >> 5;
        __align__(16) __half v[8];
        #pragma unroll
        for (int e = 0; e < 8; ++e) v[e] = xl_lds[(c*8 + e)*DD + f];
        *(uint4*)&xlT_swz[((f*16) + (c ^ (f & 7)))*8] = *(uint4*)v;
    }
    __syncthreads();                                   // B1: Slq/swz ready

    __align__(16) __half2 lv[16];
    float pm0, pm1, lbuf = 0.f;

    // ---- PASS A: dstA = dl ----
    LOGIT_LOOP(fSA)
    rp[sg*CC + dstA] = fmaxf(pm0, pm1);
    __syncthreads();                                   // B2: rp[A] ready
    EXP_PHASE(dstA)
    WRITE_P(PfragA, dstA)                              // upper region: no hazard

    // ---- load xr for dstB (xrA dead) ----
    float fSB;
    {
        uint4 XB[4];
        const uint4* pb = (const uint4*)(xr_h + ((size_t)bh*CC + dstB)*DD);
        #pragma unroll
        for (int c = 0; c < 4; ++c) XB[c] = pb[c];
        const __half2* vb = (const __half2*)XB;
        float sB = 0.f;
        #pragma unroll
        for (int i = 0; i < 16; ++i) {
            xr2[i] = vb[i];
            __half2 p = __hmul2(qa2[i], xr2[i]);
            sB += __low2float(p) + __high2float(p);
        }
        fSB = 1.5f * sB;
    }

    // ---- PASS B: dstB = dl + 64 (rp/sp slots disjoint from A's) ----
    LOGIT_LOOP(fSB)
    rp[sg*CC + dstB] = fmaxf(pm0, pm1);
    __syncthreads();                                   // B3: rp[B] ready
    EXP_PHASE(dstB)
    __syncthreads();                                   // B4: sp[A]+sp[B] ready

    // row inverse-sums -> Sg (sg==0 only)
    if (sg == 0) {
        float isA = 1.f / (((sp[0*CC + dstA] + sp[1*CC + dstA]) +
                            (sp[2*CC + dstA] + sp[3*CC + dstA])) + 1e-16f);
        float isB = 1.f / (((sp[0*CC + dstB] + sp[1*CC + dstB]) +
                            (sp[2*CC + dstB] + sp[3*CC + dstB])) + 1e-16f);
        Sg[(size_t)bh*CC + dstA] = isA;
        Sg[(size_t)bh*CC + dstB] = isB;
    }
    __syncthreads();                                   // B5: sp reads done -> overlay OK
    WRITE_P(PfragB, dstB)                              // lower region (over dead xl)
    __syncthreads();                                   // B6: P complete

    // ---- PV on MFMA: wave sg owns rows sg*32..+31; output UNNORMALIZED ----
    int quad = dl >> 4, mr = dl & 15;
    f16x8 afr[2][4];
    #pragma unroll
    for (int mf = 0; mf < 2; ++mf) {
        int dr0 = sg*2 + mf;                           // global row>>4
        const __half* base = (dr0 < 4) ? PfragA : PfragB;
        int drl = dr0 & 3;
        #pragma unroll
        for (int ks = 0; ks < 4; ++ks)
            afr[mf][ks] = *(const f16x8*)&base[((drl*4 + ks)*64 + SLOT(quad, mr))*8];
    }
    f32x4 acc[2][2];
    #pragma unroll
    for (int i = 0; i < 2; ++i)
        #pragma unroll
        for (int j = 0; j < 2; ++j) acc[i][j] = (f32x4){0.f,0.f,0.f,0.f};
    #pragma unroll
    for (int ks = 0; ks < 4; ++ks) {
        int ca = ks*4 + quad;
        f16x8 bfr2[2];
        #pragma unroll
        for (int nf = 0; nf < 2; ++nf) {
            int n = nf*16 + mr;
            bfr2[nf] = *(const f16x8*)&xlT_swz[((n*16) + (ca ^ (n & 7)))*8];
        }
        #pragma unroll
        for (int mf = 0; mf < 2; ++mf)
            #pragma unroll
            for (int nf = 0; nf < 2; ++nf)
                acc[mf][nf] = __builtin_amdgcn_mfma_f32_16x16x32_f16(afr[mf][ks], bfr2[nf], acc[mf][nf], 0, 0, 0);
    }
    #pragma unroll
    for (int mf = 0; mf < 2; ++mf)
        #pragma unroll
        for (int nf = 0; nf < 2; ++nf) {
            int f = nf*16 + mr;
            #pragma unroll
            for (int r = 0; r < 4; ++r) {
                int node = sg*32 + mf*16 + quad*4 + r;
                xagg[(((size_t)b*CC + node)*HH + h)*DD + f] = __float2half(acc[mf][nf][r]);
            }
        }
}

// ---------------------------------------------------------------------------
// K6: fused L1-epilogue + attention-map assembly + projection GEMM (512 thr,
// R10 structure). h1' (post-LN) never touches global; attn normalized via Sg.
// ---------------------------------------------------------------------------
__global__ __launch_bounds__(512) void epi_proj(const __half* __restrict__ xagg,
                                                const float* __restrict__ gbias,
                                                const float* __restrict__ ln_g,
                                                const float* __restrict__ ln_b,
                                                const float* __restrict__ Sg,
                                                const __half* __restrict__ Pg,
                                                const ushort* __restrict__ WpT,
                                                const float* __restrict__ pbias,
                                                ushort* __restrict__ hmat,
                                                float* __restrict__ out,
                                                float* __restrict__ attn_out) {
    __shared__ __align__(16) ushort Als[128*16*8];
    __shared__ __align__(16) ushort Bls[128*16*8];
    int b = blockIdx.x, t = threadIdx.x;
    const float* Sg_b = Sg + (size_t)b*HH*CC;
    epilogue_to_tile512(xagg, gbias, ln_g, ln_b, Sg_b, hmat, Bls, b, t, false);

    // attention map rows: attn[node][src] = 0.25 * sum_h p[h][nl][src]*is[h][nl]
    {
        int nl = t >> 2, fq = t & 3;
        int node = b*CC + nl;
        float ish[HH];
        #pragma unroll
        for (int hh = 0; hh < HH; ++hh) ish[hh] = Sg_b[hh*CC + nl];
        #pragma unroll
        for (int c = 0; c < 4; ++c) {
            float a[8] = {0.f,0.f,0.f,0.f,0.f,0.f,0.f,0.f};
            #pragma unroll
            for (int hh = 0; hh < HH; ++hh) {
                uint4 pu = *(const uint4*)&Pg[((size_t)(b*HH + hh)*CC + nl)*CC + fq*32 + c*8];
                const __half2* pv = (const __half2*)&pu;
                #pragma unroll
                for (int i = 0; i < 4; ++i) {
                    a[2*i]   += __low2float(pv[i]) * ish[hh];
                    a[2*i+1] += __high2float(pv[i]) * ish[hh];
                }
            }
            float4 o0, o1;
            o0.x = 0.25f*a[0]; o0.y = 0.25f*a[1]; o0.z = 0.25f*a[2]; o0.w = 0.25f*a[3];
            o1.x = 0.25f*a[4]; o1.y = 0.25f*a[5]; o1.z = 0.25f*a[6]; o1.w = 0.25f*a[7];
            *(float4*)&attn_out[(size_t)node*CC + fq*32 + c*8]     = o0;
            *(float4*)&attn_out[(size_t)node*CC + fq*32 + c*8 + 4] = o1;
        }
    }

    int lane = t & 63, w = t >> 6;
    int mr = lane & 15, quad = lane >> 4;
    #pragma unroll
    for (int half = 0; half < 2; ++half) {
        __syncthreads();
        stage_bf16_rm512(Als, WpT + (size_t)half*128*HIDD, HIDD, t);
        __syncthreads();
        f32x4 acc[8];
        ZERO_ACC8(acc)
        mfma_tile_512(Als, Bls, acc, w, lane);
        #pragma unroll
        for (int nf = 0; nf < 8; ++nf) {
            int c = nf*16 + mr;
            #pragma unroll
            for (int r = 0; r < 4; ++r) {
                int l = half*128 + w*16 + quad*4 + r;
                out[((size_t)b*LL + l)*CC + c] = acc[nf][r] + pbias[l];
            }
        }
    }
}

// ---------------------------------------------------------------------------
extern "C" void kernel_launch(void* const* d_in, const int* in_sizes, int n_in,
                              void* d_out, int out_size, void* d_ws, size_t ws_size,
                              hipStream_t stream) {
    const float* x        = (const float*)d_in[0];
    const int*   edge     = (const int*)d_in[1];
    const float* emb_W    = (const float*)d_in[2];
    const float* emb_b    = (const float*)d_in[3];
    const float* lin_l_W  = (const float*)d_in[4];
    const float* lin_l_b  = (const float*)d_in[5];
    const float* lin_r_W  = (const float*)d_in[6];
    const float* lin_r_b  = (const float*)d_in[7];
    const float* att      = (const float*)d_in[8];
    const float* gat_bias = (const float*)d_in[9];
    const float* ln_g     = (const float*)d_in[10];
    const float* ln_b     = (const float*)d_in[11];
    const float* proj_W   = (const float*)d_in[12];
    const float* proj_b   = (const float*)d_in[13];

    // workspace: h(bf16) | xl | xr | xagg | Pg | mult | Sg | W
    ushort* h     = (ushort*)d_ws;
    __half* xl_h  = (__half*)(h + (size_t)NN * HIDD);
    __half* xr_h  = xl_h + (size_t)NN * HIDD;
    __half* xagg  = xr_h + (size_t)NN * HIDD;
    __half* Pg    = xagg + (size_t)NN * HIDD;
    __half* mult_ds = Pg + (size_t)BB * HH * CC * CC;
    float*  Sg    = (float*)(mult_ds + (size_t)CC * CC);
    ushort* WembT = (ushort*)(Sg + (size_t)BB * HH * CC);
    ushort* WlrT  = WembT + (size_t)CC*LL;
    ushort* WpT   = WlrT + (size_t)4*HIDD*HIDD;

    float* out0 = (float*)d_out;                       // (B, L, C)
    float* attn = out0 + (size_t)BB * LL * CC;         // (B, C, C)

    prep_weights<<<65, 256, 0, stream>>>(emb_W, lin_l_W, lin_r_W, proj_W, edge,
                                         WembT, WlrT, WpT, mult_ds);
    embed_lin<<<BB, 512, 0, stream>>>(x, WembT, emb_b,
                                      WlrT, WlrT + (size_t)HIDD*HIDD,
                                      lin_l_b, lin_r_b, h, xl_h, xr_h);
    gat_fused<<<BB*HH, 256, 0, stream>>>(xl_h, xr_h, mult_ds, att, xagg, Sg, nullptr);
    epi_lin<<<BB, 512, 0, stream>>>(xagg, gat_bias, ln_g, ln_b, Sg,
                                    WlrT + (size_t)2*HIDD*HIDD,
                                    WlrT + (size_t)3*HIDD*HIDD,
                                    lin_l_b + HIDD, lin_r_b + HIDD,
                                    h, xl_h, xr_h);
    gat_fused<<<BB*HH, 256, 0, stream>>>(xl_h, xr_h, mult_ds, att + HIDD, xagg, Sg, Pg);
    epi_proj<<<BB, 512, 0, stream>>>(xagg, gat_bias + HIDD, ln_g + HIDD, ln_b + HIDD,
                                     Sg, Pg, WpT, proj_b, h, out0, attn);
}